// Round 1
// 257.923 us; speedup vs baseline: 1.4622x; 1.4622x over previous
//
#include <hip/hip_runtime.h>

constexpr int Bn = 65536;
constexpr int Cn = 4096;
constexpr int Dn = 128;
constexpr float TAU = 0.03f;  // key err std ~3.4e-3 (f16 x); 6-sigma pairwise guard

typedef _Float16 v8h __attribute__((ext_vector_type(8)));
typedef float v16f __attribute__((ext_vector_type(16)));

#define MFMA16(a, b, c) __builtin_amdgcn_mfma_f32_32x32x16_f16((a), (b), (c), 0, 0, 0)

// ---------------------------------------------------------------------------
// Pack codes into MFMA A-fragment order as 2-term f16 planes, PRE-SCALED -2.
// Also computes cnorm (fp64) inline, writes a f32 transposed copy codesT[d][c]
// (for the coalesced rescore), and zeroes flagcount.
// Tile ct (128 tiles, 9216 halves = 18432 B):
//   slice s in [0,8): hi @ ct*9216 + s*1024 + l*8, lo @ +512
//   slice 8: 3-term f16 split of (cnorm[code] + 512) at k=0,1,2 (lanes l<32);
//            with B=ones at k=0..2 one MFMA makes acc = key+512 directly
//            (+512 keeps keys positive => u32-sortable floats).
// ---------------------------------------------------------------------------
__global__ void pack_codes_kernel(const float* __restrict__ codes,
                                  float* __restrict__ cnorm,
                                  _Float16* __restrict__ pack,
                                  float* __restrict__ codesT,
                                  int* __restrict__ flagcount) {
  int tid = blockIdx.x * 256 + threadIdx.x;  // 288 blocks -> 1152 wave-frags
  if (tid == 0) *flagcount = 0;
  int f = tid >> 6;
  int l = tid & 63;
  int ct = f / 9, s = f % 9;
  int code = (ct << 5) + (l & 31);
  if (s < 8) {
    int kb = (s << 4) + ((l >> 5) << 3);
    const float* p = codes + (size_t)code * Dn + kb;
    float4 a = ((const float4*)p)[0];
    float4 b = ((const float4*)p)[1];
    float v[8] = {a.x, a.y, a.z, a.w, b.x, b.y, b.z, b.w};
    // f32 transpose for the rescore path (raw values, no -2 scale)
#pragma unroll
    for (int j = 0; j < 8; ++j)
      codesT[(size_t)(kb + j) * Cn + code] = v[j];
    v8h hi, lo;
#pragma unroll
    for (int j = 0; j < 8; ++j) {
      float sv = -2.f * v[j];  // exact scale
      _Float16 h = (_Float16)sv;
      hi[j] = h;
      lo[j] = (_Float16)(sv - (float)h);
    }
    *(v8h*)(pack + (size_t)ct * 9216 + s * 1024 + l * 8) = hi;
    *(v8h*)(pack + (size_t)ct * 9216 + s * 1024 + 512 + l * 8) = lo;
  } else {
    v8h a = {0, 0, 0, 0, 0, 0, 0, 0};
    if (l < 32) {
      const float4* p = (const float4*)(codes + (size_t)code * Dn);
      double sd = 0.0;
#pragma unroll
      for (int i = 0; i < Dn / 4; ++i) {
        float4 v = p[i];
        sd += (double)v.x * v.x + (double)v.y * v.y + (double)v.z * v.z +
              (double)v.w * v.w;
      }
      float cn = (float)sd;
      cnorm[code] = cn;
      float c5 = cn + 512.f;
      _Float16 h1 = (_Float16)c5;
      float r1 = c5 - (float)h1;
      _Float16 h2 = (_Float16)r1;
      float r2 = r1 - (float)h2;
      _Float16 h3 = (_Float16)r2;
      a[0] = h1;
      a[1] = h2;
      a[2] = h3;
    }
    v8h z = {0, 0, 0, 0, 0, 0, 0, 0};
    *(v8h*)(pack + (size_t)ct * 9216 + 8 * 1024 + l * 8) = a;
    *(v8h*)(pack + (size_t)ct * 9216 + 8 * 1024 + 512 + l * 8) = z;
  }
}

// ---------------------------------------------------------------------------
// Main: LDS-staged code-split sweep (proven structure). Per tile per wave:
// 17 ds_read_b128 -> 34 MFMA (2 f16 product terms x 2 accs x 8 ks + 2 cnorm).
// acc[r] = key + 512 (always positive). Branchless epilogue: pack 4-bit r
// into low mantissa bits, v_min_u32 trees for (min, exact in-tile 2nd, idx).
// C/D 32x32: col = lane&31 = x-row, code-row = (r&3)+8*(r>>2)+4*(lane>>5).
// ---------------------------------------------------------------------------
__launch_bounds__(256, 2)
__global__ void argmin_mfma_kernel(const float* __restrict__ x,
                                   const _Float16* __restrict__ pack,
                                   float* __restrict__ pm1,
                                   float* __restrict__ pm2,
                                   float* __restrict__ pidx) {
  __shared__ __align__(16) _Float16 packLDS[2][9216];  // 2 x 18 KB

  const int t = threadIdx.x;
  const int w = t >> 6;
  const int l = t & 63;
  const int h = blockIdx.x & 1;
  const int row0 = (blockIdx.x >> 1) * 256;

  // x fragments -> registers (single f16). Wave w: rows row0+w*64+tt*32+(l&31).
  v8h xh[2][8];
#pragma unroll
  for (int tt = 0; tt < 2; ++tt) {
#pragma unroll
    for (int ks = 0; ks < 8; ++ks) {
      int xrow = row0 + w * 64 + tt * 32 + (l & 31);
      int kb = ks * 16 + (l >> 5) * 8;
      const float* xp = x + (size_t)xrow * Dn + kb;
      float4 a = ((const float4*)xp)[0];
      float4 b = ((const float4*)xp)[1];
      float v[8] = {a.x, a.y, a.z, a.w, b.x, b.y, b.z, b.w};
      v8h hh;
#pragma unroll
      for (int j = 0; j < 8; ++j) hh[j] = (_Float16)v[j];
      xh[tt][ks] = hh;
    }
  }

  // B fragment of f16 ones at k=0,1,2 (pairs with the cnorm A-slice).
  v8h bones;
#pragma unroll
  for (int j = 0; j < 8; ++j)
    bones[j] = (l < 32 && j < 3) ? (_Float16)1.0f : (_Float16)0.0f;

  v16f zacc;
#pragma unroll
  for (int i = 0; i < 16; ++i) zacc[i] = 0.f;

  const char* packbase = (const char*)pack + (size_t)(h * 64) * 18432;
  auto stage = [&](int ct, int bufi) {
    const char* src = packbase + (size_t)ct * 18432 + l * 16;
    char* dstb = (char*)&packLDS[bufi][0];
    for (int i = w; i < 18; i += 4) {
      __builtin_amdgcn_global_load_lds(
          (const __attribute__((address_space(1))) unsigned*)(src + i * 1024),
          (__attribute__((address_space(3))) unsigned*)(dstb + i * 1024), 16,
          0, 0);
    }
  };

  stage(0, 0);
  __syncthreads();

  float min1[2] = {3.4e38f, 3.4e38f};
  float min2[2] = {3.4e38f, 3.4e38f};
  int idx[2] = {0, 0};

  auto update = [&](const v16f& a, int tt, int codebase) {
    // pack r into low 4 mantissa bits (keys positive => u32 order = f32 order)
    unsigned b[16];
#pragma unroll
    for (int r = 0; r < 16; ++r)
      b[r] = (__float_as_uint(a[r]) & 0xFFFFFFF0u) | (unsigned)r;
    // tree1: min + index
    unsigned m0 = min(min(min(b[0], b[1]), min(b[2], b[3])),
                      min(min(b[4], b[5]), min(b[6], b[7])));
    unsigned m1 = min(min(min(b[8], b[9]), min(b[10], b[11])),
                      min(min(b[12], b[13]), min(b[14], b[15])));
    unsigned u1 = min(m0, m1);
    // mask winner (packed values unique by r), tree2: exact in-tile 2nd
    unsigned c[16];
#pragma unroll
    for (int r = 0; r < 16; ++r) c[r] = (b[r] == u1) ? 0xFFFFFFFFu : b[r];
    unsigned n0 = min(min(min(c[0], c[1]), min(c[2], c[3])),
                      min(min(c[4], c[5]), min(c[6], c[7])));
    unsigned n1 = min(min(min(c[8], c[9]), min(c[10], c[11])),
                      min(min(c[12], c[13]), min(c[14], c[15])));
    unsigned u2 = min(n0, n1);

    float t1 = __uint_as_float(u1 & 0xFFFFFFF0u);
    float t2 = __uint_as_float(u2 & 0xFFFFFFF0u);
    unsigned r1 = u1 & 15u;
    int tidx = codebase + (int)(8 * (r1 >> 2) + (r1 & 3));
    bool lt = t1 < min1[tt];
    min2[tt] = lt ? fminf(min1[tt], t2) : fminf(min2[tt], t1);
    idx[tt] = lt ? tidx : idx[tt];
    min1[tt] = lt ? t1 : min1[tt];
  };

  for (int it = 0; it < 64; ++it) {
    const int buf = it & 1;
    if (it + 1 < 64) stage(it + 1, buf ^ 1);

    const _Float16* base = &packLDS[buf][l * 8];
    v8h a_cn = *(const v8h*)(base + 8 * 1024);
    v16f acc0 = MFMA16(a_cn, bones, zacc);  // acc = cnorm+512
    v16f acc1 = MFMA16(a_cn, bones, zacc);
#pragma unroll
    for (int s = 0; s < 8; ++s) {
      v8h a_h = *(const v8h*)(base + s * 1024);
      v8h a_l = *(const v8h*)(base + s * 1024 + 512);
      acc0 = MFMA16(a_h, xh[0][s], acc0);
      acc1 = MFMA16(a_h, xh[1][s], acc1);
      acc0 = MFMA16(a_l, xh[0][s], acc0);
      acc1 = MFMA16(a_l, xh[1][s], acc1);
    }

    const int codebase = h * 2048 + it * 32 + 4 * (l >> 5);
    update(acc0, 0, codebase);
    update(acc1, 1, codebase);
    __syncthreads();
  }

  // Merge lane pair (l, l^32): same x-row, complementary code rows.
#pragma unroll
  for (int tt = 0; tt < 2; ++tt) {
    float o1 = __shfl_xor(min1[tt], 32);
    float o2 = __shfl_xor(min2[tt], 32);
    int oi = __shfl_xor(idx[tt], 32);
    bool sw = (o1 < min1[tt]) || (o1 == min1[tt] && oi < idx[tt]);
    float n1 = sw ? o1 : min1[tt];
    int ni = sw ? oi : idx[tt];
    float big = sw ? min1[tt] : o1;
    float n2 = fminf(fminf(min2[tt], o2), big);
    if (l < 32) {
      int row = row0 + w * 64 + tt * 32 + l;
      pm1[h * Bn + row] = n1;
      pm2[h * Bn + row] = n2;
      pidx[h * Bn + row] = (float)ni;
    }
  }
}

// ---------------------------------------------------------------------------
// Merge the two code-half partials; write idxf; flag small-margin rows.
// (pm values live in key+512 space; margins are shift-invariant.)
// ---------------------------------------------------------------------------
__global__ void merge_kernel(const float* __restrict__ pm1,
                             const float* __restrict__ pm2,
                             const float* __restrict__ pidx,
                             float* __restrict__ idxf,
                             int* __restrict__ flaglist,
                             int* __restrict__ flagcount) {
  int r = blockIdx.x * 256 + threadIdx.x;
  float a1 = pm1[r], b1 = pm1[Bn + r];
  float a2 = pm2[r], b2 = pm2[Bn + r];
  float ai = pidx[r], bi = pidx[Bn + r];
  bool a = (a1 <= b1);
  float m1 = a ? a1 : b1;
  float mi = a ? ai : bi;
  float m2 = a ? fminf(a2, b1) : fminf(b2, a1);
  idxf[r] = mi;
  if (m2 - m1 < TAU) {
    int p = atomicAdd(flagcount, 1);
    flaglist[p] = r;
  }
}

// ---------------------------------------------------------------------------
// Exact fp32 rescore of flagged rows, coalesced via codesT[d][c].
// Work item wi = 4*row_j + quarter_q; each block scores 1024 codes for one
// flagged row. Lane t owns codes c0..c0+3 (float4 per d => 1KB/wave coalesced,
// 4 independent fmaf chains). Per-code fmaf order over d is IDENTICAL to the
// previous (passing) rescore => bit-identical keys; all reductions are
// lexicographic min on (key, idx) => partition-independent result.
// ---------------------------------------------------------------------------
__global__ void rescore_part_kernel(const float* __restrict__ x,
                                    const float* __restrict__ codesT,
                                    const float* __restrict__ cnorm,
                                    const int* __restrict__ flaglist,
                                    const int* __restrict__ flagcount,
                                    float* __restrict__ prv,
                                    int* __restrict__ pri) {
  __shared__ __align__(16) float xrow[Dn];
  __shared__ float wv[4];
  __shared__ int wis[4];
  const int t = threadIdx.x;
  const int total = 4 * (*flagcount);

  for (int wi = blockIdx.x; wi < total; wi += gridDim.x) {
    const int j = wi >> 2;
    const int q = wi & 3;
    const int r = flaglist[j];
    __syncthreads();
    if (t < 32) ((float4*)xrow)[t] = ((const float4*)(x + (size_t)r * Dn))[t];
    __syncthreads();

    const int c0 = q * 1024 + 4 * t;
    const float* cp = codesT + c0;
    float4 s = {0.f, 0.f, 0.f, 0.f};
#pragma unroll 4
    for (int d = 0; d < Dn; ++d) {
      float xv = xrow[d];
      float4 cv = *(const float4*)(cp + (size_t)d * Cn);
      s.x = fmaf(cv.x, xv, s.x);
      s.y = fmaf(cv.y, xv, s.y);
      s.z = fmaf(cv.z, xv, s.z);
      s.w = fmaf(cv.w, xv, s.w);
    }
    float k0 = fmaf(-2.f, s.x, cnorm[c0]);
    float k1 = fmaf(-2.f, s.y, cnorm[c0 + 1]);
    float k2 = fmaf(-2.f, s.z, cnorm[c0 + 2]);
    float k3 = fmaf(-2.f, s.w, cnorm[c0 + 3]);
    float bv = k0;
    int bi = c0;
    if (k1 < bv) { bv = k1; bi = c0 + 1; }
    if (k2 < bv) { bv = k2; bi = c0 + 2; }
    if (k3 < bv) { bv = k3; bi = c0 + 3; }
    // wave-level lexicographic-min reduce (64 lanes)
#pragma unroll
    for (int off = 32; off > 0; off >>= 1) {
      float ov = __shfl_down(bv, off);
      int oi = __shfl_down(bi, off);
      if (ov < bv || (ov == bv && oi < bi)) { bv = ov; bi = oi; }
    }
    if ((t & 63) == 0) { wv[t >> 6] = bv; wis[t >> 6] = bi; }
    __syncthreads();
    if (t == 0) {
#pragma unroll
      for (int k = 1; k < 4; ++k) {
        if (wv[k] < bv || (wv[k] == bv && wis[k] < bi)) {
          bv = wv[k];
          bi = wis[k];
        }
      }
      prv[wi] = bv;
      pri[wi] = bi;
    }
  }
}

// ---------------------------------------------------------------------------
// Merge the 4 per-quarter partials of each flagged row -> idxf.
// ---------------------------------------------------------------------------
__global__ void rescore_final_kernel(const int* __restrict__ flaglist,
                                     const int* __restrict__ flagcount,
                                     const float* __restrict__ prv,
                                     const int* __restrict__ pri,
                                     float* __restrict__ idxf) {
  const int cnt = *flagcount;
  for (int j = blockIdx.x * blockDim.x + threadIdx.x; j < cnt;
       j += gridDim.x * blockDim.x) {
    float bv = prv[4 * j];
    int bi = pri[4 * j];
#pragma unroll
    for (int k = 1; k < 4; ++k) {
      float ov = prv[4 * j + k];
      int oi = pri[4 * j + k];
      if (ov < bv || (ov == bv && oi < bi)) { bv = ov; bi = oi; }
    }
    idxf[flaglist[j]] = (float)bi;
  }
}

// ---------------------------------------------------------------------------
// Gather + per-block loss partial (no global atomics).
// ---------------------------------------------------------------------------
__global__ void gather_loss_kernel(const float* __restrict__ x,
                                   const float* __restrict__ codes,
                                   const float* __restrict__ idxf,
                                   float* __restrict__ quant,
                                   float* __restrict__ partial) {
  __shared__ float part[8];
  const int t = threadIdx.x;
  const int wave = t >> 6;
  const int lane = t & 63;
  const int half = lane >> 5;
  const int l = lane & 31;
  const int base = blockIdx.x * 32;

  float s = 0.f;
#pragma unroll
  for (int pass = 0; pass < 4; ++pass) {
    int row = base + pass * 8 + (wave << 1) + half;
    int idx = (int)idxf[row];
    float4 cv = ((const float4*)(codes + (size_t)idx * Dn))[l];
    float4 xv = ((const float4*)(x + (size_t)row * Dn))[l];
    ((float4*)(quant + (size_t)row * Dn))[l] = cv;
    float d0 = xv.x - cv.x, d1 = xv.y - cv.y, d2 = xv.z - cv.z,
          d3 = xv.w - cv.w;
    s += d0 * d0 + d1 * d1 + d2 * d2 + d3 * d3;
  }
#pragma unroll
  for (int off = 16; off > 0; off >>= 1) s += __shfl_down(s, off, 32);
  if (l == 0) part[(wave << 1) + half] = s;
  __syncthreads();
  if (t == 0) {
    float tot = 0.f;
#pragma unroll
    for (int i = 0; i < 8; ++i) tot += part[i];
    partial[blockIdx.x] = tot;
  }
}

// ---------------------------------------------------------------------------
// Final loss reduction: 2048 partials -> loss (direct write, no pre-zero).
// ---------------------------------------------------------------------------
__global__ void loss_sum_kernel(const float* __restrict__ partial,
                                float* __restrict__ loss) {
  __shared__ float red[4];
  const int t = threadIdx.x;
  float s = 0.f;
  for (int i = t; i < 2048; i += 256) s += partial[i];
#pragma unroll
  for (int off = 32; off > 0; off >>= 1) s += __shfl_down(s, off, 64);
  if ((t & 63) == 0) red[t >> 6] = s;
  __syncthreads();
  if (t == 0)
    *loss = (red[0] + red[1] + red[2] + red[3]) * (1.25f / 65536.f);
}

// ---------------------------------------------------------------------------
extern "C" void kernel_launch(void* const* d_in, const int* in_sizes, int n_in,
                              void* d_out, int out_size, void* d_ws,
                              size_t ws_size, hipStream_t stream) {
  const float* x = (const float*)d_in[0];
  const float* codes = (const float*)d_in[1];

  float* quant = (float*)d_out;            // B*D floats (scratch until gather)
  float* idxf = quant + (size_t)Bn * Dn;   // B floats
  float* loss = idxf + Bn;                 // 1 float
  float* cnorm = (float*)d_ws;             // 16 KB
  float* partial = cnorm + Cn;             // 8 KB

  _Float16* pack = (_Float16*)quant;           // 2.25 MB @ 0
  int* flagcount = (int*)(quant + (1 << 20));  // @ 4 MB
  int* flaglist = flagcount + 1;               // up to 256 KB
  float* pm1 = quant + (2 << 20);              // @ 8 MB
  float* pm2 = pm1 + 2 * Bn;
  float* pidx = pm2 + 2 * Bn;
  float* codesT = quant + (3 << 20);           // @ 12 MB, 2 MB (f32 [D][C])
  float* prv = quant + (4 << 20);              // @ 16 MB, <=1 MB
  int* pri = (int*)(quant + (4 << 20) + (1 << 18));  // @ 17 MB, <=1 MB

  pack_codes_kernel<<<288, 256, 0, stream>>>(codes, cnorm, pack, codesT,
                                             flagcount);
  argmin_mfma_kernel<<<512, 256, 0, stream>>>(x, pack, pm1, pm2, pidx);
  merge_kernel<<<Bn / 256, 256, 0, stream>>>(pm1, pm2, pidx, idxf, flaglist,
                                             flagcount);
  rescore_part_kernel<<<2048, 256, 0, stream>>>(x, codesT, cnorm, flaglist,
                                                flagcount, prv, pri);
  rescore_final_kernel<<<64, 256, 0, stream>>>(flaglist, flagcount, prv, pri,
                                               idxf);
  gather_loss_kernel<<<Bn / 32, 256, 0, stream>>>(x, codes, idxf, quant,
                                                  partial);
  loss_sum_kernel<<<1, 256, 0, stream>>>(partial, loss);
}

// Round 2
// 256.042 us; speedup vs baseline: 1.4729x; 1.0073x over previous
//
#include <hip/hip_runtime.h>

constexpr int Bn = 65536;
constexpr int Cn = 4096;
constexpr int Dn = 128;
constexpr float TAU = 0.03f;  // key err std ~3.4e-3 (f16 x); 6-sigma pairwise guard

typedef _Float16 v8h __attribute__((ext_vector_type(8)));
typedef float v16f __attribute__((ext_vector_type(16)));

#define MFMA16(a, b, c) __builtin_amdgcn_mfma_f32_32x32x16_f16((a), (b), (c), 0, 0, 0)

// ---------------------------------------------------------------------------
// Pack codes into MFMA A-fragment order as 2-term f16 planes, PRE-SCALED -2.
// Also computes cnorm (fp64) inline, writes a f32 transposed copy codesT[d][c]
// (for the coalesced rescore), and zeroes flagcount.
// Tile ct (128 tiles, 9216 halves = 18432 B):
//   slice s in [0,8): hi @ ct*9216 + s*1024 + l*8, lo @ +512
//   slice 8: 3-term f16 split of (cnorm[code] + 512) at k=0,1,2 (lanes l<32);
//            with B=ones at k=0..2 one MFMA makes acc = key+512 directly
//            (+512 keeps keys positive => u32-sortable floats).
// ---------------------------------------------------------------------------
__global__ void pack_codes_kernel(const float* __restrict__ codes,
                                  float* __restrict__ cnorm,
                                  _Float16* __restrict__ pack,
                                  float* __restrict__ codesT,
                                  int* __restrict__ flagcount) {
  int tid = blockIdx.x * 256 + threadIdx.x;  // 288 blocks -> 1152 wave-frags
  if (tid == 0) *flagcount = 0;
  int f = tid >> 6;
  int l = tid & 63;
  int ct = f / 9, s = f % 9;
  int code = (ct << 5) + (l & 31);
  if (s < 8) {
    int kb = (s << 4) + ((l >> 5) << 3);
    const float* p = codes + (size_t)code * Dn + kb;
    float4 a = ((const float4*)p)[0];
    float4 b = ((const float4*)p)[1];
    float v[8] = {a.x, a.y, a.z, a.w, b.x, b.y, b.z, b.w};
    // f32 transpose for the rescore path (raw values, no -2 scale)
#pragma unroll
    for (int j = 0; j < 8; ++j)
      codesT[(size_t)(kb + j) * Cn + code] = v[j];
    v8h hi, lo;
#pragma unroll
    for (int j = 0; j < 8; ++j) {
      float sv = -2.f * v[j];  // exact scale
      _Float16 h = (_Float16)sv;
      hi[j] = h;
      lo[j] = (_Float16)(sv - (float)h);
    }
    *(v8h*)(pack + (size_t)ct * 9216 + s * 1024 + l * 8) = hi;
    *(v8h*)(pack + (size_t)ct * 9216 + s * 1024 + 512 + l * 8) = lo;
  } else {
    v8h a = {0, 0, 0, 0, 0, 0, 0, 0};
    if (l < 32) {
      const float4* p = (const float4*)(codes + (size_t)code * Dn);
      double sd = 0.0;
#pragma unroll
      for (int i = 0; i < Dn / 4; ++i) {
        float4 v = p[i];
        sd += (double)v.x * v.x + (double)v.y * v.y + (double)v.z * v.z +
              (double)v.w * v.w;
      }
      float cn = (float)sd;
      cnorm[code] = cn;
      float c5 = cn + 512.f;
      _Float16 h1 = (_Float16)c5;
      float r1 = c5 - (float)h1;
      _Float16 h2 = (_Float16)r1;
      float r2 = r1 - (float)h2;
      _Float16 h3 = (_Float16)r2;
      a[0] = h1;
      a[1] = h2;
      a[2] = h3;
    }
    v8h z = {0, 0, 0, 0, 0, 0, 0, 0};
    *(v8h*)(pack + (size_t)ct * 9216 + 8 * 1024 + l * 8) = a;
    *(v8h*)(pack + (size_t)ct * 9216 + 8 * 1024 + 512 + l * 8) = z;
  }
}

// ---------------------------------------------------------------------------
// Main: LDS-staged code-QUARTER sweep, 4 accs/wave. Per tile per wave:
// 17 ds_read_b128 -> 68 MFMA (2 f16 terms x 4 accs x 8 ks + 4 cnorm-init).
// Each 17KB tile read now feeds 128 x-rows (4 accs) instead of 64 -> LDS
// bytes per output halved vs the 2-acc version (LDS was the top pipe cost).
// Block: 512 x-rows x 1024 codes (quarter h = blockIdx.x & 3, 32 tiles).
// acc[r] = key + 512 (always positive). Branchless epilogue: pack 4-bit r
// into low mantissa bits, v_min_u32 trees for (min, exact in-tile 2nd, idx).
// C/D 32x32: col = lane&31 = x-row, code-row = (r&3)+8*(r>>2)+4*(lane>>5).
// ---------------------------------------------------------------------------
__launch_bounds__(256, 2)
__global__ void argmin_mfma_kernel(const float* __restrict__ x,
                                   const _Float16* __restrict__ pack,
                                   float* __restrict__ pm1,
                                   float* __restrict__ pm2,
                                   float* __restrict__ pidx) {
  __shared__ __align__(16) _Float16 packLDS[2][9216];  // 2 x 18 KB

  const int t = threadIdx.x;
  const int w = t >> 6;
  const int l = t & 63;
  const int h = blockIdx.x & 3;
  const int row0 = (blockIdx.x >> 2) * 512;

  // x fragments -> registers (single f16). Wave w: rows row0+w*128+tt*32+(l&31).
  v8h xh[4][8];
#pragma unroll
  for (int tt = 0; tt < 4; ++tt) {
#pragma unroll
    for (int ks = 0; ks < 8; ++ks) {
      int xrow = row0 + w * 128 + tt * 32 + (l & 31);
      int kb = ks * 16 + (l >> 5) * 8;
      const float* xp = x + (size_t)xrow * Dn + kb;
      float4 a = ((const float4*)xp)[0];
      float4 b = ((const float4*)xp)[1];
      float v[8] = {a.x, a.y, a.z, a.w, b.x, b.y, b.z, b.w};
      v8h hh;
#pragma unroll
      for (int j = 0; j < 8; ++j) hh[j] = (_Float16)v[j];
      xh[tt][ks] = hh;
    }
  }

  // B fragment of f16 ones at k=0,1,2 (pairs with the cnorm A-slice).
  v8h bones;
#pragma unroll
  for (int j = 0; j < 8; ++j)
    bones[j] = (l < 32 && j < 3) ? (_Float16)1.0f : (_Float16)0.0f;

  v16f zacc;
#pragma unroll
  for (int i = 0; i < 16; ++i) zacc[i] = 0.f;

  const char* packbase = (const char*)pack + (size_t)(h * 32) * 18432;
  auto stage = [&](int ct, int bufi) {
    const char* src = packbase + (size_t)ct * 18432 + l * 16;
    char* dstb = (char*)&packLDS[bufi][0];
    for (int i = w; i < 18; i += 4) {
      __builtin_amdgcn_global_load_lds(
          (const __attribute__((address_space(1))) unsigned*)(src + i * 1024),
          (__attribute__((address_space(3))) unsigned*)(dstb + i * 1024), 16,
          0, 0);
    }
  };

  stage(0, 0);
  __syncthreads();

  float min1[4] = {3.4e38f, 3.4e38f, 3.4e38f, 3.4e38f};
  float min2[4] = {3.4e38f, 3.4e38f, 3.4e38f, 3.4e38f};
  int idx[4] = {0, 0, 0, 0};

  auto update = [&](const v16f& a, int tt, int codebase) {
    // pack r into low 4 mantissa bits (keys positive => u32 order = f32 order)
    unsigned b[16];
#pragma unroll
    for (int r = 0; r < 16; ++r)
      b[r] = (__float_as_uint(a[r]) & 0xFFFFFFF0u) | (unsigned)r;
    // tree1: min + index
    unsigned m0 = min(min(min(b[0], b[1]), min(b[2], b[3])),
                      min(min(b[4], b[5]), min(b[6], b[7])));
    unsigned m1 = min(min(min(b[8], b[9]), min(b[10], b[11])),
                      min(min(b[12], b[13]), min(b[14], b[15])));
    unsigned u1 = min(m0, m1);
    // mask winner (packed values unique by r), tree2: exact in-tile 2nd
    unsigned c[16];
#pragma unroll
    for (int r = 0; r < 16; ++r) c[r] = (b[r] == u1) ? 0xFFFFFFFFu : b[r];
    unsigned n0 = min(min(min(c[0], c[1]), min(c[2], c[3])),
                      min(min(c[4], c[5]), min(c[6], c[7])));
    unsigned n1 = min(min(min(c[8], c[9]), min(c[10], c[11])),
                      min(min(c[12], c[13]), min(c[14], c[15])));
    unsigned u2 = min(n0, n1);

    float t1 = __uint_as_float(u1 & 0xFFFFFFF0u);
    float t2 = __uint_as_float(u2 & 0xFFFFFFF0u);
    unsigned r1 = u1 & 15u;
    int tidx = codebase + (int)(8 * (r1 >> 2) + (r1 & 3));
    bool lt = t1 < min1[tt];
    min2[tt] = lt ? fminf(min1[tt], t2) : fminf(min2[tt], t1);
    idx[tt] = lt ? tidx : idx[tt];
    min1[tt] = lt ? t1 : min1[tt];
  };

  for (int it = 0; it < 32; ++it) {
    const int buf = it & 1;
    if (it + 1 < 32) stage(it + 1, buf ^ 1);

    const _Float16* base = &packLDS[buf][l * 8];
    v8h a_cn = *(const v8h*)(base + 8 * 1024);
    v16f acc0 = MFMA16(a_cn, bones, zacc);  // acc = cnorm+512
    v16f acc1 = MFMA16(a_cn, bones, zacc);
    v16f acc2 = MFMA16(a_cn, bones, zacc);
    v16f acc3 = MFMA16(a_cn, bones, zacc);
#pragma unroll
    for (int s = 0; s < 8; ++s) {
      v8h a_h = *(const v8h*)(base + s * 1024);
      v8h a_l = *(const v8h*)(base + s * 1024 + 512);
      acc0 = MFMA16(a_h, xh[0][s], acc0);
      acc1 = MFMA16(a_h, xh[1][s], acc1);
      acc2 = MFMA16(a_h, xh[2][s], acc2);
      acc3 = MFMA16(a_h, xh[3][s], acc3);
      acc0 = MFMA16(a_l, xh[0][s], acc0);
      acc1 = MFMA16(a_l, xh[1][s], acc1);
      acc2 = MFMA16(a_l, xh[2][s], acc2);
      acc3 = MFMA16(a_l, xh[3][s], acc3);
    }

    const int codebase = h * 1024 + it * 32 + 4 * (l >> 5);
    update(acc0, 0, codebase);
    update(acc1, 1, codebase);
    update(acc2, 2, codebase);
    update(acc3, 3, codebase);
    __syncthreads();
  }

  // Merge lane pair (l, l^32): same x-row, complementary code rows.
#pragma unroll
  for (int tt = 0; tt < 4; ++tt) {
    float o1 = __shfl_xor(min1[tt], 32);
    float o2 = __shfl_xor(min2[tt], 32);
    int oi = __shfl_xor(idx[tt], 32);
    bool sw = (o1 < min1[tt]) || (o1 == min1[tt] && oi < idx[tt]);
    float n1 = sw ? o1 : min1[tt];
    int ni = sw ? oi : idx[tt];
    float big = sw ? min1[tt] : o1;
    float n2 = fminf(fminf(min2[tt], o2), big);
    if (l < 32) {
      int row = row0 + w * 128 + tt * 32 + l;
      pm1[h * Bn + row] = n1;
      pm2[h * Bn + row] = n2;
      pidx[h * Bn + row] = (float)ni;
    }
  }
}

// ---------------------------------------------------------------------------
// Merge the four code-quarter partials; write idxf; flag small-margin rows.
// Exact: global m2 = min(pm2[h*], min_{h != h*} pm1[h]); sequential insert
// keeps that invariant. Ties prefer lower h (= lower code index).
// (pm values live in key+512 space; margins are shift-invariant.)
// ---------------------------------------------------------------------------
__global__ void merge_kernel(const float* __restrict__ pm1,
                             const float* __restrict__ pm2,
                             const float* __restrict__ pidx,
                             float* __restrict__ idxf,
                             int* __restrict__ flaglist,
                             int* __restrict__ flagcount) {
  int r = blockIdx.x * 256 + threadIdx.x;
  float m1 = pm1[r];
  float mw2 = pm2[r];  // pm2 of current winner quarter
  float mi = pidx[r];
  float m2 = 3.4e38f;  // min over losers' pm1
#pragma unroll
  for (int h = 1; h < 4; ++h) {
    float v1 = pm1[h * Bn + r];
    float v2 = pm2[h * Bn + r];
    float vi = pidx[h * Bn + r];
    bool win = v1 < m1;
    m2 = fminf(m2, win ? m1 : v1);
    mw2 = win ? v2 : mw2;
    mi = win ? vi : mi;
    m1 = win ? v1 : m1;
  }
  m2 = fminf(m2, mw2);
  idxf[r] = mi;
  if (m2 - m1 < TAU) {
    int p = atomicAdd(flagcount, 1);
    flaglist[p] = r;
  }
}

// ---------------------------------------------------------------------------
// Exact fp32 rescore of flagged rows, coalesced via codesT[d][c].
// Work item wi = 4*row_j + quarter_q; each block scores 1024 codes for one
// flagged row. Lane t owns codes c0..c0+3 (float4 per d => 1KB/wave coalesced,
// 4 independent fmaf chains). Per-code fmaf order over d is IDENTICAL to the
// original (passing) rescore => bit-identical keys; all reductions are
// lexicographic min on (key, idx) => partition-independent result.
// ---------------------------------------------------------------------------
__global__ void rescore_part_kernel(const float* __restrict__ x,
                                    const float* __restrict__ codesT,
                                    const float* __restrict__ cnorm,
                                    const int* __restrict__ flaglist,
                                    const int* __restrict__ flagcount,
                                    float* __restrict__ prv,
                                    int* __restrict__ pri) {
  __shared__ __align__(16) float xrow[Dn];
  __shared__ float wv[4];
  __shared__ int wis[4];
  const int t = threadIdx.x;
  const int total = 4 * (*flagcount);

  for (int wi = blockIdx.x; wi < total; wi += gridDim.x) {
    const int j = wi >> 2;
    const int q = wi & 3;
    const int r = flaglist[j];
    __syncthreads();
    if (t < 32) ((float4*)xrow)[t] = ((const float4*)(x + (size_t)r * Dn))[t];
    __syncthreads();

    const int c0 = q * 1024 + 4 * t;
    const float* cp = codesT + c0;
    float4 s = {0.f, 0.f, 0.f, 0.f};
#pragma unroll 4
    for (int d = 0; d < Dn; ++d) {
      float xv = xrow[d];
      float4 cv = *(const float4*)(cp + (size_t)d * Cn);
      s.x = fmaf(cv.x, xv, s.x);
      s.y = fmaf(cv.y, xv, s.y);
      s.z = fmaf(cv.z, xv, s.z);
      s.w = fmaf(cv.w, xv, s.w);
    }
    float k0 = fmaf(-2.f, s.x, cnorm[c0]);
    float k1 = fmaf(-2.f, s.y, cnorm[c0 + 1]);
    float k2 = fmaf(-2.f, s.z, cnorm[c0 + 2]);
    float k3 = fmaf(-2.f, s.w, cnorm[c0 + 3]);
    float bv = k0;
    int bi = c0;
    if (k1 < bv) { bv = k1; bi = c0 + 1; }
    if (k2 < bv) { bv = k2; bi = c0 + 2; }
    if (k3 < bv) { bv = k3; bi = c0 + 3; }
    // wave-level lexicographic-min reduce (64 lanes)
#pragma unroll
    for (int off = 32; off > 0; off >>= 1) {
      float ov = __shfl_down(bv, off);
      int oi = __shfl_down(bi, off);
      if (ov < bv || (ov == bv && oi < bi)) { bv = ov; bi = oi; }
    }
    if ((t & 63) == 0) { wv[t >> 6] = bv; wis[t >> 6] = bi; }
    __syncthreads();
    if (t == 0) {
#pragma unroll
      for (int k = 1; k < 4; ++k) {
        if (wv[k] < bv || (wv[k] == bv && wis[k] < bi)) {
          bv = wv[k];
          bi = wis[k];
        }
      }
      prv[wi] = bv;
      pri[wi] = bi;
    }
  }
}

// ---------------------------------------------------------------------------
// Merge the 4 per-quarter partials of each flagged row -> idxf.
// ---------------------------------------------------------------------------
__global__ void rescore_final_kernel(const int* __restrict__ flaglist,
                                     const int* __restrict__ flagcount,
                                     const float* __restrict__ prv,
                                     const int* __restrict__ pri,
                                     float* __restrict__ idxf) {
  const int cnt = *flagcount;
  for (int j = blockIdx.x * blockDim.x + threadIdx.x; j < cnt;
       j += gridDim.x * blockDim.x) {
    float bv = prv[4 * j];
    int bi = pri[4 * j];
#pragma unroll
    for (int k = 1; k < 4; ++k) {
      float ov = prv[4 * j + k];
      int oi = pri[4 * j + k];
      if (ov < bv || (ov == bv && oi < bi)) { bv = ov; bi = oi; }
    }
    idxf[flaglist[j]] = (float)bi;
  }
}

// ---------------------------------------------------------------------------
// Gather + per-block loss partial (no global atomics).
// ---------------------------------------------------------------------------
__global__ void gather_loss_kernel(const float* __restrict__ x,
                                   const float* __restrict__ codes,
                                   const float* __restrict__ idxf,
                                   float* __restrict__ quant,
                                   float* __restrict__ partial) {
  __shared__ float part[8];
  const int t = threadIdx.x;
  const int wave = t >> 6;
  const int lane = t & 63;
  const int half = lane >> 5;
  const int l = lane & 31;
  const int base = blockIdx.x * 32;

  float s = 0.f;
#pragma unroll
  for (int pass = 0; pass < 4; ++pass) {
    int row = base + pass * 8 + (wave << 1) + half;
    int idx = (int)idxf[row];
    float4 cv = ((const float4*)(codes + (size_t)idx * Dn))[l];
    float4 xv = ((const float4*)(x + (size_t)row * Dn))[l];
    ((float4*)(quant + (size_t)row * Dn))[l] = cv;
    float d0 = xv.x - cv.x, d1 = xv.y - cv.y, d2 = xv.z - cv.z,
          d3 = xv.w - cv.w;
    s += d0 * d0 + d1 * d1 + d2 * d2 + d3 * d3;
  }
#pragma unroll
  for (int off = 16; off > 0; off >>= 1) s += __shfl_down(s, off, 32);
  if (l == 0) part[(wave << 1) + half] = s;
  __syncthreads();
  if (t == 0) {
    float tot = 0.f;
#pragma unroll
    for (int i = 0; i < 8; ++i) tot += part[i];
    partial[blockIdx.x] = tot;
  }
}

// ---------------------------------------------------------------------------
// Final loss reduction: 2048 partials -> loss (direct write, no pre-zero).
// ---------------------------------------------------------------------------
__global__ void loss_sum_kernel(const float* __restrict__ partial,
                                float* __restrict__ loss) {
  __shared__ float red[4];
  const int t = threadIdx.x;
  float s = 0.f;
  for (int i = t; i < 2048; i += 256) s += partial[i];
#pragma unroll
  for (int off = 32; off > 0; off >>= 1) s += __shfl_down(s, off, 64);
  if ((t & 63) == 0) red[t >> 6] = s;
  __syncthreads();
  if (t == 0)
    *loss = (red[0] + red[1] + red[2] + red[3]) * (1.25f / 65536.f);
}

// ---------------------------------------------------------------------------
extern "C" void kernel_launch(void* const* d_in, const int* in_sizes, int n_in,
                              void* d_out, int out_size, void* d_ws,
                              size_t ws_size, hipStream_t stream) {
  const float* x = (const float*)d_in[0];
  const float* codes = (const float*)d_in[1];

  float* quant = (float*)d_out;            // B*D floats (scratch until gather)
  float* idxf = quant + (size_t)Bn * Dn;   // B floats
  float* loss = idxf + Bn;                 // 1 float
  float* cnorm = (float*)d_ws;             // 16 KB
  float* partial = cnorm + Cn;             // 8 KB

  _Float16* pack = (_Float16*)quant;           // 2.25 MB @ 0
  int* flagcount = (int*)(quant + (1 << 20));  // @ 4 MB
  int* flaglist = flagcount + 1;               // up to 256 KB
  float* pm1 = quant + (2 << 20);              // @ 8 MB, 1 MB (4 quarters)
  float* pm2 = pm1 + 4 * Bn;                   // @ 9 MB
  float* pidx = pm2 + 4 * Bn;                  // @ 10 MB
  float* codesT = quant + (3 << 20);           // @ 12 MB, 2 MB (f32 [D][C])
  float* prv = quant + (4 << 20);              // @ 16 MB, <=1 MB
  int* pri = (int*)(quant + (4 << 20) + (1 << 18));  // @ 17 MB, <=1 MB

  pack_codes_kernel<<<288, 256, 0, stream>>>(codes, cnorm, pack, codesT,
                                             flagcount);
  argmin_mfma_kernel<<<512, 256, 0, stream>>>(x, pack, pm1, pm2, pidx);
  merge_kernel<<<Bn / 256, 256, 0, stream>>>(pm1, pm2, pidx, idxf, flaglist,
                                             flagcount);
  rescore_part_kernel<<<2048, 256, 0, stream>>>(x, codesT, cnorm, flaglist,
                                                flagcount, prv, pri);
  rescore_final_kernel<<<64, 256, 0, stream>>>(flaglist, flagcount, prv, pri,
                                               idxf);
  gather_loss_kernel<<<Bn / 32, 256, 0, stream>>>(x, codes, idxf, quant,
                                                  partial);
  loss_sum_kernel<<<1, 256, 0, stream>>>(partial, loss);
}

// Round 3
// 231.015 us; speedup vs baseline: 1.6325x; 1.1083x over previous
//
#include <hip/hip_runtime.h>

constexpr int Bn = 65536;
constexpr int Cn = 4096;
constexpr int Dn = 128;
// Pairwise key-err: x-side f16 std ~3.4e-3 (validated at TAU=0.03, 6 sigma);
// c-side now single-f16 => same magnitude, independent => sqrt(2) scale
// (0.042) + u32-mask granularity (~2e-3) + headroom => TAU = 0.055.
constexpr float TAU = 0.055f;

typedef _Float16 v8h __attribute__((ext_vector_type(8)));
typedef float v16f __attribute__((ext_vector_type(16)));

#define MFMA16(a, b, c) __builtin_amdgcn_mfma_f32_32x32x16_f16((a), (b), (c), 0, 0, 0)

// ---------------------------------------------------------------------------
// Pack codes into MFMA A-fragment order as SINGLE f16 planes, PRE-SCALED -2.
// Also computes cnorm (fp64) inline, writes a f32 transposed copy codesT[d][c]
// (for the coalesced rescore), and zeroes flagcount.
// Tile ct (128 tiles, 4608 halves = 9216 B):
//   slice s in [0,8): hi @ ct*4608 + s*512 + l*8
//   slice 8: 3-term f16 split of (cnorm[code] + 512) at k=0,1,2 (lanes l<32);
//            with B=ones at k=0..2 one MFMA makes acc = key+512 directly
//            (+512 keeps keys positive => u32-sortable floats).
// ---------------------------------------------------------------------------
__global__ void pack_codes_kernel(const float* __restrict__ codes,
                                  float* __restrict__ cnorm,
                                  _Float16* __restrict__ pack,
                                  float* __restrict__ codesT,
                                  int* __restrict__ flagcount) {
  int tid = blockIdx.x * 256 + threadIdx.x;  // 288 blocks -> 1152 wave-frags
  if (tid == 0) *flagcount = 0;
  int f = tid >> 6;
  int l = tid & 63;
  int ct = f / 9, s = f % 9;
  int code = (ct << 5) + (l & 31);
  if (s < 8) {
    int kb = (s << 4) + ((l >> 5) << 3);
    const float* p = codes + (size_t)code * Dn + kb;
    float4 a = ((const float4*)p)[0];
    float4 b = ((const float4*)p)[1];
    float v[8] = {a.x, a.y, a.z, a.w, b.x, b.y, b.z, b.w};
    // f32 transpose for the rescore path (raw values, no -2 scale)
#pragma unroll
    for (int j = 0; j < 8; ++j)
      codesT[(size_t)(kb + j) * Cn + code] = v[j];
    v8h hi;
#pragma unroll
    for (int j = 0; j < 8; ++j) {
      float sv = -2.f * v[j];  // exact scale
      hi[j] = (_Float16)sv;    // single-term f16 (rescore covers the error)
    }
    *(v8h*)(pack + (size_t)ct * 4608 + s * 512 + l * 8) = hi;
  } else {
    v8h a = {0, 0, 0, 0, 0, 0, 0, 0};
    if (l < 32) {
      const float4* p = (const float4*)(codes + (size_t)code * Dn);
      double sd = 0.0;
#pragma unroll
      for (int i = 0; i < Dn / 4; ++i) {
        float4 v = p[i];
        sd += (double)v.x * v.x + (double)v.y * v.y + (double)v.z * v.z +
              (double)v.w * v.w;
      }
      float cn = (float)sd;
      cnorm[code] = cn;
      float c5 = cn + 512.f;
      _Float16 h1 = (_Float16)c5;
      float r1 = c5 - (float)h1;
      _Float16 h2 = (_Float16)r1;
      float r2 = r1 - (float)h2;
      _Float16 h3 = (_Float16)r2;
      a[0] = h1;
      a[1] = h2;
      a[2] = h3;
    }
    *(v8h*)(pack + (size_t)ct * 4608 + 8 * 512 + l * 8) = a;
  }
}

// ---------------------------------------------------------------------------
// Main: LDS-staged code-QUARTER sweep, 4 accs/wave, SINGLE f16 term.
// Per tile per wave: 9 ds_read_b128 -> 36 MFMA (4 cnorm-init + 8 ks x 4 accs).
// Block: 512 x-rows x 1024 codes (quarter h = blockIdx.x & 3, 32 tiles).
// acc[r] = key + 512 (always positive). Branchless epilogue: pack 4-bit r
// into low mantissa bits; pair-merge network gives exact (min, in-tile 2nd,
// idx) in u32 domain (positive keys => u32 order = f32 order).
// C/D 32x32: col = lane&31 = x-row, code-row = (r&3)+8*(r>>2)+4*(lane>>5).
// ---------------------------------------------------------------------------
__launch_bounds__(256, 2)
__global__ void argmin_mfma_kernel(const float* __restrict__ x,
                                   const _Float16* __restrict__ pack,
                                   float* __restrict__ pm1,
                                   float* __restrict__ pm2,
                                   float* __restrict__ pidx) {
  __shared__ __align__(16) _Float16 packLDS[2][4608];  // 2 x 9 KB

  const int t = threadIdx.x;
  const int w = t >> 6;
  const int l = t & 63;
  const int h = blockIdx.x & 3;
  const int row0 = (blockIdx.x >> 2) * 512;

  // x fragments -> registers (single f16). Wave w: rows row0+w*128+tt*32+(l&31).
  v8h xh[4][8];
#pragma unroll
  for (int tt = 0; tt < 4; ++tt) {
#pragma unroll
    for (int ks = 0; ks < 8; ++ks) {
      int xrow = row0 + w * 128 + tt * 32 + (l & 31);
      int kb = ks * 16 + (l >> 5) * 8;
      const float* xp = x + (size_t)xrow * Dn + kb;
      float4 a = ((const float4*)xp)[0];
      float4 b = ((const float4*)xp)[1];
      float v[8] = {a.x, a.y, a.z, a.w, b.x, b.y, b.z, b.w};
      v8h hh;
#pragma unroll
      for (int j = 0; j < 8; ++j) hh[j] = (_Float16)v[j];
      xh[tt][ks] = hh;
    }
  }

  // B fragment of f16 ones at k=0,1,2 (pairs with the cnorm A-slice).
  v8h bones;
#pragma unroll
  for (int j = 0; j < 8; ++j)
    bones[j] = (l < 32 && j < 3) ? (_Float16)1.0f : (_Float16)0.0f;

  v16f zacc;
#pragma unroll
  for (int i = 0; i < 16; ++i) zacc[i] = 0.f;

  const char* packbase = (const char*)pack + (size_t)(h * 32) * 9216;
  auto stage = [&](int ct, int bufi) {
    const char* src = packbase + (size_t)ct * 9216 + l * 16;
    char* dstb = (char*)&packLDS[bufi][0];
    for (int i = w; i < 9; i += 4) {
      __builtin_amdgcn_global_load_lds(
          (const __attribute__((address_space(1))) unsigned*)(src + i * 1024),
          (__attribute__((address_space(3))) unsigned*)(dstb + i * 1024), 16,
          0, 0);
    }
  };

  stage(0, 0);
  __syncthreads();

  // Cross-tile state in packed-u32 domain (keys positive).
  unsigned umin1[4] = {0xFFFFFFFFu, 0xFFFFFFFFu, 0xFFFFFFFFu, 0xFFFFFFFFu};
  unsigned umin2[4] = {0xFFFFFFFFu, 0xFFFFFFFFu, 0xFFFFFFFFu, 0xFFFFFFFFu};
  int idx[4] = {0, 0, 0, 0};

  auto update = [&](const v16f& a, int tt, int codebase) {
    // pack r into low 4 mantissa bits (values then unique; u32 order = f32)
    unsigned b[16];
#pragma unroll
    for (int r = 0; r < 16; ++r)
      b[r] = (__float_as_uint(a[r]) & 0xFFFFFFF0u) | (unsigned)r;
    // pair-merge network: exact (m1, m2) of 16 values.
    // Invariant: (m1,m2) = two smallest seen; merging sorted pair (lo,hi):
    //   m1' = min(m1,lo); m2' = min(min(m2,hi), max(m1,lo))   [exact]
    unsigned m1 = 0xFFFFFFFFu, m2 = 0xFFFFFFFFu;
#pragma unroll
    for (int i = 0; i < 8; ++i) {
      unsigned lo = min(b[2 * i], b[2 * i + 1]);
      unsigned hi = max(b[2 * i], b[2 * i + 1]);
      unsigned mx = max(m1, lo);
      m1 = min(m1, lo);
      m2 = min(min(m2, hi), mx);
    }
    unsigned r1 = m1 & 15u;
    int tidx = codebase + (int)(8 * (r1 >> 2) + (r1 & 3));
    bool lt = m1 < umin1[tt];
    umin2[tt] = lt ? min(umin1[tt], m2) : min(umin2[tt], m1);
    idx[tt] = lt ? tidx : idx[tt];
    umin1[tt] = lt ? m1 : umin1[tt];
  };

  for (int it = 0; it < 32; ++it) {
    const int buf = it & 1;
    if (it + 1 < 32) stage(it + 1, buf ^ 1);

    const _Float16* base = &packLDS[buf][l * 8];
    v8h a_cn = *(const v8h*)(base + 8 * 512);
    v16f acc0 = MFMA16(a_cn, bones, zacc);  // acc = cnorm+512
    v16f acc1 = MFMA16(a_cn, bones, zacc);
    v16f acc2 = MFMA16(a_cn, bones, zacc);
    v16f acc3 = MFMA16(a_cn, bones, zacc);
#pragma unroll
    for (int s = 0; s < 8; ++s) {
      v8h a_h = *(const v8h*)(base + s * 512);
      acc0 = MFMA16(a_h, xh[0][s], acc0);
      acc1 = MFMA16(a_h, xh[1][s], acc1);
      acc2 = MFMA16(a_h, xh[2][s], acc2);
      acc3 = MFMA16(a_h, xh[3][s], acc3);
    }

    const int codebase = h * 1024 + it * 32 + 4 * (l >> 5);
    update(acc0, 0, codebase);
    update(acc1, 1, codebase);
    update(acc2, 2, codebase);
    update(acc3, 3, codebase);
    __syncthreads();
  }

  // Merge lane pair (l, l^32): same x-row, complementary code rows.
#pragma unroll
  for (int tt = 0; tt < 4; ++tt) {
    unsigned o1 = (unsigned)__shfl_xor((int)umin1[tt], 32);
    unsigned o2 = (unsigned)__shfl_xor((int)umin2[tt], 32);
    int oi = __shfl_xor(idx[tt], 32);
    bool sw = (o1 < umin1[tt]) || (o1 == umin1[tt] && oi < idx[tt]);
    unsigned n1 = sw ? o1 : umin1[tt];
    int ni = sw ? oi : idx[tt];
    unsigned big = sw ? umin1[tt] : o1;
    unsigned n2 = min(min(umin2[tt], o2), big);
    if (l < 32) {
      int row = row0 + w * 128 + tt * 32 + l;
      pm1[h * Bn + row] = __uint_as_float(n1 & 0xFFFFFFF0u);
      pm2[h * Bn + row] = __uint_as_float(n2 & 0xFFFFFFF0u);
      pidx[h * Bn + row] = (float)ni;
    }
  }
}

// ---------------------------------------------------------------------------
// Merge the four code-quarter partials; write idxf; flag small-margin rows.
// Exact: global m2 = min(pm2[h*], min_{h != h*} pm1[h]); sequential insert
// keeps that invariant. Ties prefer lower h (= lower code index).
// (pm values live in key+512 space; margins are shift-invariant.)
// ---------------------------------------------------------------------------
__global__ void merge_kernel(const float* __restrict__ pm1,
                             const float* __restrict__ pm2,
                             const float* __restrict__ pidx,
                             float* __restrict__ idxf,
                             int* __restrict__ flaglist,
                             int* __restrict__ flagcount) {
  int r = blockIdx.x * 256 + threadIdx.x;
  float m1 = pm1[r];
  float mw2 = pm2[r];  // pm2 of current winner quarter
  float mi = pidx[r];
  float m2 = 3.4e38f;  // min over losers' pm1
#pragma unroll
  for (int h = 1; h < 4; ++h) {
    float v1 = pm1[h * Bn + r];
    float v2 = pm2[h * Bn + r];
    float vi = pidx[h * Bn + r];
    bool win = v1 < m1;
    m2 = fminf(m2, win ? m1 : v1);
    mw2 = win ? v2 : mw2;
    mi = win ? vi : mi;
    m1 = win ? v1 : m1;
  }
  m2 = fminf(m2, mw2);
  idxf[r] = mi;
  if (m2 - m1 < TAU) {
    int p = atomicAdd(flagcount, 1);
    flaglist[p] = r;
  }
}

// ---------------------------------------------------------------------------
// Exact fp32 rescore of flagged rows, coalesced via codesT[d][c].
// Work item wi = 4*row_j + quarter_q; each block scores 1024 codes for one
// flagged row. Lane t owns codes c0..c0+3 (float4 per d => 1KB/wave coalesced,
// 4 independent fmaf chains). Per-code fmaf order over d is IDENTICAL to the
// original (passing) rescore => bit-identical keys; all reductions are
// lexicographic min on (key, idx) => partition-independent result.
// ---------------------------------------------------------------------------
__global__ void rescore_part_kernel(const float* __restrict__ x,
                                    const float* __restrict__ codesT,
                                    const float* __restrict__ cnorm,
                                    const int* __restrict__ flaglist,
                                    const int* __restrict__ flagcount,
                                    float* __restrict__ prv,
                                    int* __restrict__ pri) {
  __shared__ __align__(16) float xrow[Dn];
  __shared__ float wv[4];
  __shared__ int wis[4];
  const int t = threadIdx.x;
  const int total = 4 * (*flagcount);

  for (int wi = blockIdx.x; wi < total; wi += gridDim.x) {
    const int j = wi >> 2;
    const int q = wi & 3;
    const int r = flaglist[j];
    __syncthreads();
    if (t < 32) ((float4*)xrow)[t] = ((const float4*)(x + (size_t)r * Dn))[t];
    __syncthreads();

    const int c0 = q * 1024 + 4 * t;
    const float* cp = codesT + c0;
    float4 s = {0.f, 0.f, 0.f, 0.f};
#pragma unroll 4
    for (int d = 0; d < Dn; ++d) {
      float xv = xrow[d];
      float4 cv = *(const float4*)(cp + (size_t)d * Cn);
      s.x = fmaf(cv.x, xv, s.x);
      s.y = fmaf(cv.y, xv, s.y);
      s.z = fmaf(cv.z, xv, s.z);
      s.w = fmaf(cv.w, xv, s.w);
    }
    float k0 = fmaf(-2.f, s.x, cnorm[c0]);
    float k1 = fmaf(-2.f, s.y, cnorm[c0 + 1]);
    float k2 = fmaf(-2.f, s.z, cnorm[c0 + 2]);
    float k3 = fmaf(-2.f, s.w, cnorm[c0 + 3]);
    float bv = k0;
    int bi = c0;
    if (k1 < bv) { bv = k1; bi = c0 + 1; }
    if (k2 < bv) { bv = k2; bi = c0 + 2; }
    if (k3 < bv) { bv = k3; bi = c0 + 3; }
    // wave-level lexicographic-min reduce (64 lanes)
#pragma unroll
    for (int off = 32; off > 0; off >>= 1) {
      float ov = __shfl_down(bv, off);
      int oi = __shfl_down(bi, off);
      if (ov < bv || (ov == bv && oi < bi)) { bv = ov; bi = oi; }
    }
    if ((t & 63) == 0) { wv[t >> 6] = bv; wis[t >> 6] = bi; }
    __syncthreads();
    if (t == 0) {
#pragma unroll
      for (int k = 1; k < 4; ++k) {
        if (wv[k] < bv || (wv[k] == bv && wis[k] < bi)) {
          bv = wv[k];
          bi = wis[k];
        }
      }
      prv[wi] = bv;
      pri[wi] = bi;
    }
  }
}

// ---------------------------------------------------------------------------
// Merge the 4 per-quarter partials of each flagged row -> idxf.
// ---------------------------------------------------------------------------
__global__ void rescore_final_kernel(const int* __restrict__ flaglist,
                                     const int* __restrict__ flagcount,
                                     const float* __restrict__ prv,
                                     const int* __restrict__ pri,
                                     float* __restrict__ idxf) {
  const int cnt = *flagcount;
  for (int j = blockIdx.x * blockDim.x + threadIdx.x; j < cnt;
       j += gridDim.x * blockDim.x) {
    float bv = prv[4 * j];
    int bi = pri[4 * j];
#pragma unroll
    for (int k = 1; k < 4; ++k) {
      float ov = prv[4 * j + k];
      int oi = pri[4 * j + k];
      if (ov < bv || (ov == bv && oi < bi)) { bv = ov; bi = oi; }
    }
    idxf[flaglist[j]] = (float)bi;
  }
}

// ---------------------------------------------------------------------------
// Gather + per-block loss partial (no global atomics).
// ---------------------------------------------------------------------------
__global__ void gather_loss_kernel(const float* __restrict__ x,
                                   const float* __restrict__ codes,
                                   const float* __restrict__ idxf,
                                   float* __restrict__ quant,
                                   float* __restrict__ partial) {
  __shared__ float part[8];
  const int t = threadIdx.x;
  const int wave = t >> 6;
  const int lane = t & 63;
  const int half = lane >> 5;
  const int l = lane & 31;
  const int base = blockIdx.x * 32;

  float s = 0.f;
#pragma unroll
  for (int pass = 0; pass < 4; ++pass) {
    int row = base + pass * 8 + (wave << 1) + half;
    int idx = (int)idxf[row];
    float4 cv = ((const float4*)(codes + (size_t)idx * Dn))[l];
    float4 xv = ((const float4*)(x + (size_t)row * Dn))[l];
    ((float4*)(quant + (size_t)row * Dn))[l] = cv;
    float d0 = xv.x - cv.x, d1 = xv.y - cv.y, d2 = xv.z - cv.z,
          d3 = xv.w - cv.w;
    s += d0 * d0 + d1 * d1 + d2 * d2 + d3 * d3;
  }
#pragma unroll
  for (int off = 16; off > 0; off >>= 1) s += __shfl_down(s, off, 32);
  if (l == 0) part[(wave << 1) + half] = s;
  __syncthreads();
  if (t == 0) {
    float tot = 0.f;
#pragma unroll
    for (int i = 0; i < 8; ++i) tot += part[i];
    partial[blockIdx.x] = tot;
  }
}

// ---------------------------------------------------------------------------
// Final loss reduction: 2048 partials -> loss (direct write, no pre-zero).
// ---------------------------------------------------------------------------
__global__ void loss_sum_kernel(const float* __restrict__ partial,
                                float* __restrict__ loss) {
  __shared__ float red[4];
  const int t = threadIdx.x;
  float s = 0.f;
  for (int i = t; i < 2048; i += 256) s += partial[i];
#pragma unroll
  for (int off = 32; off > 0; off >>= 1) s += __shfl_down(s, off, 64);
  if ((t & 63) == 0) red[t >> 6] = s;
  __syncthreads();
  if (t == 0)
    *loss = (red[0] + red[1] + red[2] + red[3]) * (1.25f / 65536.f);
}

// ---------------------------------------------------------------------------
extern "C" void kernel_launch(void* const* d_in, const int* in_sizes, int n_in,
                              void* d_out, int out_size, void* d_ws,
                              size_t ws_size, hipStream_t stream) {
  const float* x = (const float*)d_in[0];
  const float* codes = (const float*)d_in[1];

  float* quant = (float*)d_out;            // B*D floats (scratch until gather)
  float* idxf = quant + (size_t)Bn * Dn;   // B floats
  float* loss = idxf + Bn;                 // 1 float
  float* cnorm = (float*)d_ws;             // 16 KB
  float* partial = cnorm + Cn;             // 8 KB

  _Float16* pack = (_Float16*)quant;           // 1.125 MB @ 0
  int* flagcount = (int*)(quant + (1 << 20));  // @ 4 MB
  int* flaglist = flagcount + 1;               // up to 256 KB
  float* pm1 = quant + (2 << 20);              // @ 8 MB, 1 MB (4 quarters)
  float* pm2 = pm1 + 4 * Bn;                   // @ 9 MB
  float* pidx = pm2 + 4 * Bn;                  // @ 10 MB
  float* codesT = quant + (3 << 20);           // @ 12 MB, 2 MB (f32 [D][C])
  float* prv = quant + (4 << 20);              // @ 16 MB, <=1 MB
  int* pri = (int*)(quant + (4 << 20) + (1 << 18));  // @ 17 MB, <=1 MB

  pack_codes_kernel<<<288, 256, 0, stream>>>(codes, cnorm, pack, codesT,
                                             flagcount);
  argmin_mfma_kernel<<<512, 256, 0, stream>>>(x, pack, pm1, pm2, pidx);
  merge_kernel<<<Bn / 256, 256, 0, stream>>>(pm1, pm2, pidx, idxf, flaglist,
                                             flagcount);
  rescore_part_kernel<<<2048, 256, 0, stream>>>(x, codesT, cnorm, flaglist,
                                                flagcount, prv, pri);
  rescore_final_kernel<<<64, 256, 0, stream>>>(flaglist, flagcount, prv, pri,
                                               idxf);
  gather_loss_kernel<<<Bn / 32, 256, 0, stream>>>(x, codes, idxf, quant,
                                                  partial);
  loss_sum_kernel<<<1, 256, 0, stream>>>(partial, loss);
}